// Round 2
// baseline (90.231 us; speedup 1.0000x reference)
//
#include <hip/hip_runtime.h>
#include <cstdint>

#define MAXOPS 128
struct OpsArg { int n; uint32_t ops[MAXOPS]; };

// ---------- host-side replication of np.random.RandomState(1234) ----------
namespace nprng {
struct MT { uint32_t mt[624]; int mti; };
static void seed(MT& s, uint32_t sd){
  s.mt[0]=sd;
  for(uint32_t i=1;i<624;i++) s.mt[i]=1812433253u*(s.mt[i-1]^(s.mt[i-1]>>30))+i;
  s.mti=624;
}
static uint32_t next32(MT& s){
  if(s.mti>=624){
    for(int k=0;k<624;k++){
      uint32_t y=(s.mt[k]&0x80000000u)|(s.mt[(k+1)%624]&0x7fffffffu);
      s.mt[k]=s.mt[(k+397)%624]^(y>>1)^((y&1u)?0x9908b0dfu:0u);
    }
    s.mti=0;
  }
  uint32_t y=s.mt[s.mti++];
  y^=y>>11; y^=(y<<7)&0x9d2c5680u; y^=(y<<15)&0xefc60000u; y^=y>>18;
  return y;
}
static double rand01(MT& s){            // legacy random_sample
  uint32_t a=next32(s)>>5, b=next32(s)>>6;
  return (a*67108864.0+(double)b)/9007199254740992.0;
}
// Masked-rejection bounded draw on next_uint32 — used by BOTH randint (range
// <= 32-bit shortcut in random_bounded_uint64_fill) and shuffle's
// random_interval. Returns uniform in [0, mx] inclusive.
static int bounded32(MT& s, uint32_t mx){
  if(!mx) return 0;
  uint32_t m=mx; m|=m>>1;m|=m>>2;m|=m>>4;m|=m>>8;m|=m>>16;
  uint32_t v; do{ v=next32(s)&m; }while(v>mx);
  return (int)v;
}
} // namespace nprng

// op encoding: bit0 type (0=rot,1=cnot); rot: kind bits1-2 (0RX 1RY 2RZ), wire bits3-4, widx bits9-13
//              cnot: control bits1-2, target bits3-4
static void build_ops_host(OpsArg& A){
  nprng::MT s; nprng::seed(s,1234u);
  A.n=0;
  for(int l=0;l<4;l++){
    int i=0;
    while(i<8 && A.n<MAXOPS){
      if(nprng::rand01(s) > 0.3){
        int kind = nprng::bounded32(s,2); // choice of 3 -> randint(0,3), 32-bit path
        int w    = nprng::bounded32(s,3); // randint(4), 32-bit path
        A.ops[A.n++] = 0u | ((uint32_t)kind<<1) | ((uint32_t)w<<3) | ((uint32_t)(l*8+i)<<9);
        i++;
      } else {
        int a[4]={0,1,2,3};              // permutation(4) = Fisher-Yates via random_interval
        for(int ii=3; ii>=1; --ii){
          int j=nprng::bounded32(s,(uint32_t)ii);
          int t=a[ii]; a[ii]=a[j]; a[j]=t;
        }
        A.ops[A.n++] = 1u | ((uint32_t)a[0]<<1) | ((uint32_t)a[1]<<3);
      }
    }
  }
}

// ---------- prep: build U[x][b] (16x16 complex) from weights ----------
// thread t: column b = t>>4 (initial basis state), amplitude index x = t&15.
// wire w <-> bit (8>>w) of the flattened index (wire0 = MSB, C-order flatten).
__global__ __launch_bounds__(256) void qonv_prep(OpsArg A, const float* __restrict__ wts,
                                                 float* __restrict__ Ug){
  int t = threadIdx.x;
  int b = t>>4, x = t&15;
  float re = (x==b)?1.f:0.f, im=0.f;
  for(int k=0;k<A.n;k++){
    uint32_t op = A.ops[k];
    if((op&1u)==0u){
      int kind=(op>>1)&3, w=(op>>3)&3, widx=(op>>9)&31;
      float th = wts[widx];
      float hc=__cosf(0.5f*th), hs=__sinf(0.5f*th);
      int m = 8>>w;
      if(kind==2){ // RZ: diag(e^{-i th/2}, e^{+i th/2})
        float sg = (x&m)? hs : -hs;
        float nr = re*hc - im*sg;
        float ni = re*sg + im*hc;
        re=nr; im=ni;
      } else {
        float pre = __shfl_xor(re, m, 64); // partner amplitude (same column b)
        float pim = __shfl_xor(im, m, 64);
        if(kind==0){ // RX: new = c*self + (-i s)*partner
          float nr = hc*re + hs*pim;
          float ni = hc*im - hs*pre;
          re=nr; im=ni;
        } else {     // RY: bit0: c*a0 - s*a1 ; bit1: s*a0 + c*a1
          float sg = (x&m)? hs : -hs;
          float nr = hc*re + sg*pre;
          float ni = hc*im + sg*pim;
          re=nr; im=ni;
        }
      }
    } else { // CNOT(c,t): if control bit set, take partner (target-flipped) amp
      int c=(op>>1)&3, tt=(op>>3)&3;
      int cm=8>>c, tm=8>>tt;
      float pre = __shfl_xor(re, tm, 64);
      float pim = __shfl_xor(im, tm, 64);
      if(x & cm){ re=pre; im=pim; }
    }
  }
  // layout: float2 per (x,b): Ug[(x*16+b)*2 + {0,1}]
  Ug[(x*16+b)*2+0]=re;
  Ug[(x*16+b)*2+1]=im;
}

// ---------- main: 256 compute blocks (4 patches/thread) + 768 zero-fill blocks ----------
__global__ __launch_bounds__(256) void qonv_main(const float* __restrict__ img,
                                                 const float* __restrict__ Ug,
                                                 float* __restrict__ out){
  __shared__ float4 uS[128]; // 2KB: (re_b,im_b,re_{b+1},im_{b+1}) for b=2n, at [x*8+n]
  int bid = blockIdx.x;
  int tid = threadIdx.x;
  if(bid < 256){
    if(tid < 128) uS[tid] = ((const float4*)Ug)[tid];
    __syncthreads();
    int bb = bid >> 4;        // batch 0..15
    int jg = bid & 15;        // j-group
    int ty = tid >> 5;        // 0..7
    int tx = tid & 31;        // 0..31
    int j  = jg*8 + ty;       // patch row 0..127
    int k0 = tx*4;            // patch col base, 4 patches/thread
    const float* row0 = img + ((size_t)bb*512 + 2*j)*512 + 2*k0;
    float4 a0 = ((const float4*)row0)[0];
    float4 a1 = ((const float4*)row0)[1];
    float4 b0 = ((const float4*)(row0+512))[0];
    float4 b1 = ((const float4*)(row0+512))[1];
    float r0[8] = {a0.x,a0.y,a0.z,a0.w,a1.x,a1.y,a1.z,a1.w};
    float r1[8] = {b0.x,b0.y,b0.z,b0.w,b1.x,b1.y,b1.z,b1.w};

    float vv[4][16];
    #pragma unroll
    for(int p=0;p<4;p++){
      float t0=r0[2*p], t1=r0[2*p+1], t2=r1[2*p], t3=r1[2*p+1]; // tl,tr,bl,br -> wires 0..3
      float c0=__cosf(0.5f*t0), s0=__sinf(0.5f*t0);
      float c1=__cosf(0.5f*t1), s1=__sinf(0.5f*t1);
      float c2=__cosf(0.5f*t2), s2=__sinf(0.5f*t2);
      float c3=__cosf(0.5f*t3), s3=__sinf(0.5f*t3);
      float a01[4]={c0*c1, c0*s1, s0*c1, s0*s1};
      float a23[4]={c2*c3, c2*s3, s2*c3, s2*s3};
      #pragma unroll
      for(int n=0;n<16;n++) vv[p][n]=a01[n>>2]*a23[n&3];
    }

    float e[4][4];
    #pragma unroll
    for(int p=0;p<4;p++){ e[p][0]=0.f;e[p][1]=0.f;e[p][2]=0.f;e[p][3]=0.f; }

    #pragma unroll
    for(int x=0;x<16;x++){
      float re[4]={0.f,0.f,0.f,0.f}, im[4]={0.f,0.f,0.f,0.f};
      #pragma unroll
      for(int n=0;n<8;n++){
        float4 q = uS[x*8+n];
        #pragma unroll
        for(int p=0;p<4;p++){
          re[p] += q.x*vv[p][2*n] + q.z*vv[p][2*n+1];
          im[p] += q.y*vv[p][2*n] + q.w*vv[p][2*n+1];
        }
      }
      #pragma unroll
      for(int p=0;p<4;p++){
        float pr = re[p]*re[p] + im[p]*im[p];
        #pragma unroll
        for(int c=0;c<4;c++)
          e[p][c] += (x & (8>>c)) ? -pr : pr;   // <Z_c>: + if bit(3-c)==0
      }
    }

    float4* o4 = (float4*)out;
    size_t obase = ((size_t)bb*256 + j)*256 + k0;
    #pragma unroll
    for(int p=0;p<4;p++)
      o4[obase+p] = make_float4(e[p][0],e[p][1],e[p][2],e[p][3]);
  } else {
    // zero-fill complement: rows>=128 (full) and rows<128, cols>=128.
    // one thread = 4 consecutive float4s (64B).
    int q = (bid-256)*256 + tid;           // 0..196607 chunks
    size_t base;
    if(q < 131072){                        // region A: r in [128,256), all c: 64 chunks/row
      int b  = q >> 13;                    // /(128*64)
      int rm = q & 8191;
      int r  = 128 + (rm >> 6);
      int cc = (rm & 63) << 2;             // c base (float4 units)
      base = ((size_t)b*256 + r)*256 + cc;
    } else {                               // region B: r in [0,128), c in [128,256): 32 chunks/row
      int qb = q - 131072;
      int b  = qb >> 12;                   // /(128*32)
      int rm = qb & 4095;
      int r  = rm >> 5;
      int cc = 128 + ((rm & 31) << 2);
      base = ((size_t)b*256 + r)*256 + cc;
    }
    float4* o4 = (float4*)out;
    float4 z = make_float4(0.f,0.f,0.f,0.f);
    #pragma unroll
    for(int p=0;p<4;p++) o4[base+p] = z;
  }
}

extern "C" void kernel_launch(void* const* d_in, const int* in_sizes, int n_in,
                              void* d_out, int out_size, void* d_ws, size_t ws_size,
                              hipStream_t stream){
  const float* img = (const float*)d_in[0];
  const float* wts = (const float*)d_in[1];
  float* out = (float*)d_out;
  float* Ug  = (float*)d_ws;   // 512 floats (2KB) for U
  OpsArg A; build_ops_host(A);
  hipLaunchKernelGGL(qonv_prep, dim3(1),    dim3(256), 0, stream, A, wts, Ug);
  hipLaunchKernelGGL(qonv_main, dim3(1024), dim3(256), 0, stream, img, Ug, out);
}

// Round 3
// 22.283 us; speedup vs baseline: 4.0492x; 4.0492x over previous
//
#include <hip/hip_runtime.h>
#include <cstdint>

#define MAXOPS 128
struct OpsArg { int n; uint32_t ops[MAXOPS]; };

// ---------- host-side replication of np.random.RandomState(1234) ----------
namespace nprng {
struct MT { uint32_t mt[624]; int mti; };
static void seed(MT& s, uint32_t sd){
  s.mt[0]=sd;
  for(uint32_t i=1;i<624;i++) s.mt[i]=1812433253u*(s.mt[i-1]^(s.mt[i-1]>>30))+i;
  s.mti=624;
}
static uint32_t next32(MT& s){
  if(s.mti>=624){
    for(int k=0;k<624;k++){
      uint32_t y=(s.mt[k]&0x80000000u)|(s.mt[(k+1)%624]&0x7fffffffu);
      s.mt[k]=s.mt[(k+397)%624]^(y>>1)^((y&1u)?0x9908b0dfu:0u);
    }
    s.mti=0;
  }
  uint32_t y=s.mt[s.mti++];
  y^=y>>11; y^=(y<<7)&0x9d2c5680u; y^=(y<<15)&0xefc60000u; y^=y>>18;
  return y;
}
static double rand01(MT& s){
  uint32_t a=next32(s)>>5, b=next32(s)>>6;
  return (a*67108864.0+(double)b)/9007199254740992.0;
}
// masked rejection on next_uint32 (numpy 32-bit shortcut; verified round 2)
static int bounded32(MT& s, uint32_t mx){
  if(!mx) return 0;
  uint32_t m=mx; m|=m>>1;m|=m>>2;m|=m>>4;m|=m>>8;m|=m>>16;
  uint32_t v; do{ v=next32(s)&m; }while(v>mx);
  return (int)v;
}
} // namespace nprng

static void build_ops_host(OpsArg& A){
  nprng::MT s; nprng::seed(s,1234u);
  A.n=0;
  for(int l=0;l<4;l++){
    int i=0;
    while(i<8 && A.n<MAXOPS){
      if(nprng::rand01(s) > 0.3){
        int kind = nprng::bounded32(s,2);
        int w    = nprng::bounded32(s,3);
        A.ops[A.n++] = 0u | ((uint32_t)kind<<1) | ((uint32_t)w<<3) | ((uint32_t)(l*8+i)<<9);
        i++;
      } else {
        int a[4]={0,1,2,3};
        for(int ii=3; ii>=1; --ii){
          int j=nprng::bounded32(s,(uint32_t)ii);
          int t=a[ii]; a[ii]=a[j]; a[j]=t;
        }
        A.ops[A.n++] = 1u | ((uint32_t)a[0]<<1) | ((uint32_t)a[1]<<3);
      }
    }
  }
}

// ---------- prep: U (16x16) -> A_c = Re(U^T* Z_c U) -> T_c[81] monomial coeffs ----------
// e_c(patch) = sum_{a0..a3 in {1,cos,sin}^4} T_c[a] * prod_w m_{a_w}(t_w)
__global__ __launch_bounds__(256) void qonv_prep(OpsArg A, const float* __restrict__ wts,
                                                 float* __restrict__ TS){
  __shared__ float UrS[256], UiS[256], AS[1024];
  int t = threadIdx.x;
  int b = t>>4, x = t&15;
  float re = (x==b)?1.f:0.f, im=0.f;
  for(int k=0;k<A.n;k++){
    uint32_t op = A.ops[k];
    if((op&1u)==0u){
      int kind=(op>>1)&3, w=(op>>3)&3, widx=(op>>9)&31;
      float th = wts[widx];
      float hc=__cosf(0.5f*th), hs=__sinf(0.5f*th);
      int m = 8>>w;
      if(kind==2){ // RZ
        float sg = (x&m)? hs : -hs;
        float nr = re*hc - im*sg;
        float ni = re*sg + im*hc;
        re=nr; im=ni;
      } else {
        float pre = __shfl_xor(re, m, 64);
        float pim = __shfl_xor(im, m, 64);
        if(kind==0){ // RX
          float nr = hc*re + hs*pim;
          float ni = hc*im - hs*pre;
          re=nr; im=ni;
        } else {     // RY
          float sg = (x&m)? hs : -hs;
          float nr = hc*re + sg*pre;
          float ni = hc*im + sg*pim;
          re=nr; im=ni;
        }
      }
    } else { // CNOT
      int c=(op>>1)&3, tt=(op>>3)&3;
      int cm=8>>c, tm=8>>tt;
      float pre = __shfl_xor(re, tm, 64);
      float pim = __shfl_xor(im, tm, 64);
      if(x & cm){ re=pre; im=pim; }
    }
  }
  UrS[x*16+b]=re; UiS[x*16+b]=im;
  __syncthreads();
  // phase B: thread t=(bq,bp): A_c[bq][bp] = sum_x sign_c(x) (Ur[x][bq]Ur[x][bp]+Ui..Ui)
  {
    int bq = t>>4, bp = t&15;
    float a0=0.f,a1=0.f,a2=0.f,a3=0.f;
    for(int xx=0;xx<16;xx++){
      float s = UrS[xx*16+bq]*UrS[xx*16+bp] + UiS[xx*16+bq]*UiS[xx*16+bp];
      a0 += (xx&8)? -s:s;
      a1 += (xx&4)? -s:s;
      a2 += (xx&2)? -s:s;
      a3 += (xx&1)? -s:s;
    }
    AS[t*4+0]=a0; AS[t*4+1]=a1; AS[t*4+2]=a2; AS[t*4+3]=a3;
  }
  __syncthreads();
  // phase C: T_c[a] = (1/16) sum over 16 per-wire option combos of +-A_c[bq][bp]
  // per wire: a_w=0 (basis 1): (0,0)+ or (1,1)+ ; a_w=1 (cos): (0,0)+ or (1,1)- ;
  //           a_w=2 (sin): (0,1)+ or (1,0)+
  for(int s_=t; s_<324; s_+=256){
    int c = s_/81, a = s_%81;
    int ad[4] = { a/27, (a/9)%3, (a/3)%3, a%3 };
    float sum = 0.f;
    for(int k=0;k<16;k++){
      int bqq=0, bpp=0; float sg = 1.f;
      for(int w=0; w<4; w++){
        int kw = (k>>(3-w))&1;
        int aw = ad[w];
        int bw, pw;
        if(aw==2){ bw=kw; pw=1-kw; }
        else     { bw=kw; pw=kw; if(aw==1 && kw) sg = -sg; }
        bqq |= bw<<(3-w); bpp |= pw<<(3-w);
      }
      sum += sg * AS[(bqq*16+bpp)*4 + c];
    }
    TS[a*4+c] = sum * 0.0625f;
  }
}

// ---------- main: 512 compute blocks (2 patches/thread) + 768 zero-fill ----------
__global__ __launch_bounds__(256) void qonv_main(const float* __restrict__ img,
                                                 const float* __restrict__ TS,
                                                 float* __restrict__ out){
  __shared__ float4 uT[81]; // T[a01*9+a23] -> (c0,c1,c2,c3)
  int bid = blockIdx.x, tid = threadIdx.x;
  if(bid < 512){
    if(tid < 81) uT[tid] = ((const float4*)TS)[tid];
    __syncthreads();
    int bb = bid>>5, jb = bid&31;       // batch, j-group of 4 rows
    int ty = tid>>6, tx = tid&63;       // row-in-group, 2-patch column pair
    int j  = jb*4 + ty;                 // patch row 0..127
    const float* r0p = img + ((size_t)(bb*512 + 2*j))*512 + 4*tx;
    float4 ra = *(const float4*)r0p;          // img row 2j,   cols 4tx..4tx+3
    float4 rb = *(const float4*)(r0p + 512);  // img row 2j+1
    // patch A = cols (4tx,4tx+1); patch B = cols (4tx+2,4tx+3)
    float s0a,c0a,s1a,c1a,s2a,c2a,s3a,c3a;
    float s0b,c0b,s1b,c1b,s2b,c2b,s3b,c3b;
    __sincosf(ra.x,&s0a,&c0a); __sincosf(ra.y,&s1a,&c1a);
    __sincosf(rb.x,&s2a,&c2a); __sincosf(rb.y,&s3a,&c3a);
    __sincosf(ra.z,&s0b,&c0b); __sincosf(ra.w,&s1b,&c1b);
    __sincosf(rb.z,&s2b,&c2b); __sincosf(rb.w,&s3b,&c3b);
    float wA01[9] = {1.f, c1a, s1a, c0a, c0a*c1a, c0a*s1a, s0a, s0a*c1a, s0a*s1a};
    float wA23[9] = {1.f, c3a, s3a, c2a, c2a*c3a, c2a*s3a, s2a, s2a*c3a, s2a*s3a};
    float wB01[9] = {1.f, c1b, s1b, c0b, c0b*c1b, c0b*s1b, s0b, s0b*c1b, s0b*s1b};
    float wB23[9] = {1.f, c3b, s3b, c2b, c2b*c3b, c2b*s3b, s2b, s2b*c3b, s2b*s3b};
    float4 eA = make_float4(0.f,0.f,0.f,0.f);
    float4 eB = make_float4(0.f,0.f,0.f,0.f);
    #pragma unroll
    for(int a01=0;a01<9;a01++){
      float uA = wA01[a01], uB = wB01[a01];
      #pragma unroll
      for(int a23=0;a23<9;a23++){
        float4 tc = uT[a01*9+a23];
        float pA = uA*wA23[a23];
        float pB = uB*wB23[a23];
        eA.x += tc.x*pA; eA.y += tc.y*pA; eA.z += tc.z*pA; eA.w += tc.w*pA;
        eB.x += tc.x*pB; eB.y += tc.y*pB; eB.z += tc.z*pB; eB.w += tc.w*pB;
      }
    }
    float4* o4 = (float4*)out;
    size_t ob = ((size_t)bb*256 + j)*256 + 2*tx;
    o4[ob]   = eA;
    o4[ob+1] = eB;
  } else {
    // zero-fill complement: rows>=128 (all cols) and rows<128 cols>=128
    int q = (bid-512)*256 + tid;           // 0..196607 chunks of 64B
    size_t base;
    if(q < 131072){                        // region A: r in [128,256), 64 chunks/row
      int b  = q >> 13;
      int rm = q & 8191;
      int r  = 128 + (rm >> 6);
      int cc = (rm & 63) << 2;
      base = ((size_t)b*256 + r)*256 + cc;
    } else {                               // region B: r in [0,128), c in [128,256)
      int qb = q - 131072;
      int b  = qb >> 12;
      int rm = qb & 4095;
      int r  = rm >> 5;
      int cc = 128 + ((rm & 31) << 2);
      base = ((size_t)b*256 + r)*256 + cc;
    }
    float4* o4 = (float4*)out;
    float4 z = make_float4(0.f,0.f,0.f,0.f);
    #pragma unroll
    for(int p=0;p<4;p++) o4[base+p] = z;
  }
}

extern "C" void kernel_launch(void* const* d_in, const int* in_sizes, int n_in,
                              void* d_out, int out_size, void* d_ws, size_t ws_size,
                              hipStream_t stream){
  const float* img = (const float*)d_in[0];
  const float* wts = (const float*)d_in[1];
  float* out = (float*)d_out;
  float* TS  = (float*)d_ws;   // 324 floats
  OpsArg A; build_ops_host(A);
  hipLaunchKernelGGL(qonv_prep, dim3(1),    dim3(256), 0, stream, A, wts, TS);
  hipLaunchKernelGGL(qonv_main, dim3(1280), dim3(256), 0, stream, img, TS, out);
}

// Round 4
// 13.807 us; speedup vs baseline: 6.5352x; 1.6139x over previous
//
#include <hip/hip_runtime.h>
#include <cstdint>

// ---------- compile-time replication of np.random.RandomState(1234) ----------
// (verified against numpy in rounds 1-2: rand01 = 2x32-bit draws; bounded
// randint/shuffle draws use the 32-bit masked-rejection shortcut)
namespace crng {
struct MT { uint32_t mt[624]; int mti; };
constexpr MT seeded(uint32_t sd){
  MT s{}; s.mt[0]=sd;
  for(uint32_t i=1;i<624;i++) s.mt[i]=1812433253u*(s.mt[i-1]^(s.mt[i-1]>>30))+i;
  s.mti=624; return s;
}
constexpr uint32_t next32(MT& s){
  if(s.mti>=624){
    for(int k=0;k<624;k++){
      uint32_t y=(s.mt[k]&0x80000000u)|(s.mt[(k+1)%624]&0x7fffffffu);
      s.mt[k]=s.mt[(k+397)%624]^(y>>1)^((y&1u)?0x9908b0dfu:0u);
    }
    s.mti=0;
  }
  uint32_t y=s.mt[s.mti++];
  y^=y>>11; y^=(y<<7)&0x9d2c5680u; y^=(y<<15)&0xefc60000u; y^=y>>18;
  return y;
}
constexpr double rand01(MT& s){
  uint32_t a=next32(s)>>5, b=next32(s)>>6;
  return (a*67108864.0+(double)b)/9007199254740992.0;
}
constexpr int bounded32(MT& s, uint32_t mx){
  if(!mx) return 0;
  uint32_t m=mx; m|=m>>1;m|=m>>2;m|=m>>4;m|=m>>8;m|=m>>16;
  uint32_t v=next32(s)&m;
  while(v>mx){ v=next32(s)&m; }
  return (int)v;
}
} // namespace crng

struct OpsArr { int n; uint32_t ops[128]; };
// op encoding: bit0 type (0=rot,1=cnot); rot: kind bits1-2 (0RX 1RY 2RZ),
// wire bits3-4, widx bits9-13; cnot: control bits1-2, target bits3-4
constexpr OpsArr build_ops(){
  crng::MT s = crng::seeded(1234u);
  OpsArr A{}; A.n=0;
  for(int l=0;l<4;l++){
    int i=0;
    while(i<8 && A.n<128){
      if(crng::rand01(s) > 0.3){
        int kind = crng::bounded32(s,2);
        int w    = crng::bounded32(s,3);
        A.ops[A.n++] = 0u | ((uint32_t)kind<<1) | ((uint32_t)w<<3) | ((uint32_t)(l*8+i)<<9);
        i++;
      } else {
        int a[4]={0,1,2,3};
        for(int ii=3; ii>=1; --ii){
          int j=crng::bounded32(s,(uint32_t)ii);
          int t=a[ii]; a[ii]=a[j]; a[j]=t;
        }
        A.ops[A.n++] = 1u | ((uint32_t)a[0]<<1) | ((uint32_t)a[1]<<3);
      }
    }
  }
  return A;
}
constexpr OpsArr OPS_CE = build_ops();
constexpr int NOPS = OPS_CE.n;

// ---------- fused kernel ----------
// blocks 0..511:   per-block rebuild of T (81 monomial coeffs x 4 channels) in
//                  LDS (compile-time-unrolled gate sequence, ~1-2us, parallel),
//                  then 2 patches/thread polynomial contraction.
// blocks 512..1279: zero-fill of the output complement.
__global__ __launch_bounds__(256) void qonv_fused(const float* __restrict__ img,
                                                  const float* __restrict__ wts,
                                                  float* __restrict__ out){
  int bid = blockIdx.x, tid = threadIdx.x;
  if(bid < 512){
    __shared__ float UrS[256], UiS[256];
    __shared__ float AS[1024];
    __shared__ float T4S[324];
    // ---- phase A: evolve U columns. thread = (col b, amp x); wire w <-> bit (8>>w)
    {
      int b = tid>>4, x = tid&15;
      float re = (x==b)?1.f:0.f, im=0.f;
      #pragma unroll
      for(int k=0;k<NOPS;k++){
        const uint32_t op = OPS_CE.ops[k];   // compile-time constant
        if((op&1u)==0u){
          const int kind=(op>>1)&3, w=(op>>3)&3, widx=(op>>9)&31;
          float th = wts[widx];              // uniform scalar load, hoisted
          float hc=__cosf(0.5f*th), hs=__sinf(0.5f*th);
          const int m = 8>>w;
          if(kind==2){ // RZ
            float sg = (x&m)? hs : -hs;
            float nr = re*hc - im*sg;
            float ni = re*sg + im*hc;
            re=nr; im=ni;
          } else {
            float pre = __shfl_xor(re, m, 64);
            float pim = __shfl_xor(im, m, 64);
            if(kind==0){ // RX
              float nr = hc*re + hs*pim;
              float ni = hc*im - hs*pre;
              re=nr; im=ni;
            } else {     // RY
              float sg = (x&m)? hs : -hs;
              float nr = hc*re + sg*pre;
              float ni = hc*im + sg*pim;
              re=nr; im=ni;
            }
          }
        } else { // CNOT
          const int c=(op>>1)&3, tt=(op>>3)&3;
          const int cm=8>>c, tm=8>>tt;
          float pre = __shfl_xor(re, tm, 64);
          float pim = __shfl_xor(im, tm, 64);
          if(x & cm){ re=pre; im=pim; }
        }
      }
      UrS[x*16+b]=re; UiS[x*16+b]=im;
    }
    __syncthreads();
    // ---- phase B: A_c[bq][bp] = sum_x sign_c(x)(Ur[x][bq]Ur[x][bp]+Ui..Ui)
    {
      int bq = tid>>4, bp = tid&15;
      float a0=0.f,a1=0.f,a2=0.f,a3=0.f;
      #pragma unroll
      for(int xx=0;xx<16;xx++){
        float s = UrS[xx*16+bq]*UrS[xx*16+bp] + UiS[xx*16+bq]*UiS[xx*16+bp];
        a0 += (xx&8)? -s:s;
        a1 += (xx&4)? -s:s;
        a2 += (xx&2)? -s:s;
        a3 += (xx&1)? -s:s;
      }
      AS[tid*4+0]=a0; AS[tid*4+1]=a1; AS[tid*4+2]=a2; AS[tid*4+3]=a3;
    }
    __syncthreads();
    // ---- phase C: T_c[a] = (1/16) sum over 16 per-wire combos of +-A_c[bq][bp]
    for(int s_=tid; s_<324; s_+=256){
      int a = s_>>2, c = s_&3;
      int ad[4] = { a/27, (a/9)%3, (a/3)%3, a%3 };
      float sum = 0.f;
      for(int k=0;k<16;k++){
        int bqq=0, bpp=0; float sg = 1.f;
        for(int w=0; w<4; w++){
          int kw = (k>>(3-w))&1;
          int aw = ad[w];
          int bw, pw;
          if(aw==2){ bw=kw; pw=1-kw; }
          else     { bw=kw; pw=kw; if(aw==1 && kw) sg = -sg; }
          bqq |= bw<<(3-w); bpp |= pw<<(3-w);
        }
        sum += sg * AS[(bqq*16+bpp)*4 + c];
      }
      T4S[s_] = sum * 0.0625f;
    }
    __syncthreads();
    // ---- main: 2 patches/thread, e = (w01 (x) w23)^T T
    const float4* uT = (const float4*)T4S;
    int bb = bid>>5, jb = bid&31;       // batch, j-group of 4 rows
    int ty = tid>>6, tx = tid&63;       // row-in-group, 2-patch column pair
    int j  = jb*4 + ty;                 // patch row 0..127
    const float* r0p = img + ((size_t)(bb*512 + 2*j))*512 + 4*tx;
    float4 ra = *(const float4*)r0p;          // img row 2j
    float4 rb = *(const float4*)(r0p + 512);  // img row 2j+1
    float s0a,c0a,s1a,c1a,s2a,c2a,s3a,c3a;
    float s0b,c0b,s1b,c1b,s2b,c2b,s3b,c3b;
    __sincosf(ra.x,&s0a,&c0a); __sincosf(ra.y,&s1a,&c1a);
    __sincosf(rb.x,&s2a,&c2a); __sincosf(rb.y,&s3a,&c3a);
    __sincosf(ra.z,&s0b,&c0b); __sincosf(ra.w,&s1b,&c1b);
    __sincosf(rb.z,&s2b,&c2b); __sincosf(rb.w,&s3b,&c3b);
    float wA01[9] = {1.f, c1a, s1a, c0a, c0a*c1a, c0a*s1a, s0a, s0a*c1a, s0a*s1a};
    float wA23[9] = {1.f, c3a, s3a, c2a, c2a*c3a, c2a*s3a, s2a, s2a*c3a, s2a*s3a};
    float wB01[9] = {1.f, c1b, s1b, c0b, c0b*c1b, c0b*s1b, s0b, s0b*c1b, s0b*s1b};
    float wB23[9] = {1.f, c3b, s3b, c2b, c2b*c3b, c2b*s3b, s2b, s2b*c3b, s2b*s3b};
    float4 eA = make_float4(0.f,0.f,0.f,0.f);
    float4 eB = make_float4(0.f,0.f,0.f,0.f);
    #pragma unroll
    for(int a01=0;a01<9;a01++){
      float uA = wA01[a01], uB = wB01[a01];
      #pragma unroll
      for(int a23=0;a23<9;a23++){
        float4 tc = uT[a01*9+a23];
        float pA = uA*wA23[a23];
        float pB = uB*wB23[a23];
        eA.x += tc.x*pA; eA.y += tc.y*pA; eA.z += tc.z*pA; eA.w += tc.w*pA;
        eB.x += tc.x*pB; eB.y += tc.y*pB; eB.z += tc.z*pB; eB.w += tc.w*pB;
      }
    }
    float4* o4 = (float4*)out;
    size_t ob = ((size_t)bb*256 + j)*256 + 2*tx;
    o4[ob]   = eA;
    o4[ob+1] = eB;
  } else {
    // zero-fill complement: rows>=128 (all cols) and rows<128 cols>=128
    int q = (bid-512)*256 + tid;           // 64B chunks
    size_t base;
    if(q < 131072){                        // r in [128,256), 64 chunks/row
      int b  = q >> 13;
      int rm = q & 8191;
      int r  = 128 + (rm >> 6);
      int cc = (rm & 63) << 2;
      base = ((size_t)b*256 + r)*256 + cc;
    } else {                               // r in [0,128), c in [128,256)
      int qb = q - 131072;
      int b  = qb >> 12;
      int rm = qb & 4095;
      int r  = rm >> 5;
      int cc = 128 + ((rm & 31) << 2);
      base = ((size_t)b*256 + r)*256 + cc;
    }
    float4* o4 = (float4*)out;
    float4 z = make_float4(0.f,0.f,0.f,0.f);
    #pragma unroll
    for(int p=0;p<4;p++) o4[base+p] = z;
  }
}

extern "C" void kernel_launch(void* const* d_in, const int* in_sizes, int n_in,
                              void* d_out, int out_size, void* d_ws, size_t ws_size,
                              hipStream_t stream){
  const float* img = (const float*)d_in[0];
  const float* wts = (const float*)d_in[1];
  float* out = (float*)d_out;
  hipLaunchKernelGGL(qonv_fused, dim3(1280), dim3(256), 0, stream, img, wts, out);
}